// Round 3
// baseline (52.024 us; speedup 1.0000x reference)
//
#include <hip/hip_runtime.h>

#define FD 32          // feature dim
#define RPB 32         // rows per block
#define CPT 2          // cols per thread
#define BLK 256        // threads per block  -> block covers BLK*CPT = 512 cols

// packed dual-fp32 add (B is pre-negated in registers, so this computes a-b for 2 d's)
__device__ __forceinline__ float2 pk_add(float2 a, float2 b) {
    float2 r;
    asm("v_pk_add_f32 %0, %1, %2" : "=v"(r) : "v"(a), "v"(b));
    return r;
}
// acc = max(acc, |x|, |y|) in ONE VALU inst (abs is a free VOP3 input modifier)
__device__ __forceinline__ float max3abs(float a, float x, float y) {
    float r;
    asm("v_max3_f32 %0, %1, abs(%2), abs(%3)" : "=v"(r) : "v"(a), "v"(x), "v"(y));
    return r;
}

__global__ __launch_bounds__(256) void cheb_kernel(
    const float* __restrict__ A, const float* __restrict__ B,
    float* __restrict__ C, int M)
{
    const int tid = threadIdx.x;
    const int c  = blockIdx.x * (BLK * CPT) + tid * CPT;  // this thread's 2 output cols
    const int r0 = blockIdx.y * RPB;

    // ---- Load this thread's 2 B columns (negated) into registers, once.
    // B row c = 32 consecutive floats; thread reads 256B contiguous, wave reads 16KB.
    float2 nb0[16], nb1[16];
    {
        const float* b0 = B + (size_t)c * FD;
#pragma unroll
        for (int q = 0; q < 8; ++q) {
            const float4 v = *reinterpret_cast<const float4*>(b0 + q * 4);
            nb0[2 * q + 0] = make_float2(-v.x, -v.y);
            nb0[2 * q + 1] = make_float2(-v.z, -v.w);
            const float4 w = *reinterpret_cast<const float4*>(b0 + FD + q * 4);
            nb1[2 * q + 0] = make_float2(-w.x, -w.y);
            nb1[2 * q + 1] = make_float2(-w.z, -w.w);
        }
    }

    // ---- Stream A rows (wave-uniform address: L1 broadcast / scalarizable).
#pragma unroll 2
    for (int r = 0; r < RPB; ++r) {
        const float* arow = A + (size_t)(r0 + r) * FD;
        float acc0 = 0.0f, acc1 = 0.0f;   // distances are >= 0
#pragma unroll
        for (int q = 0; q < 8; ++q) {
            const float4 av = *reinterpret_cast<const float4*>(arow + q * 4);
            const float2 a01 = make_float2(av.x, av.y);
            const float2 a23 = make_float2(av.z, av.w);
            float2 d;
            d = pk_add(a01, nb0[2 * q + 0]); acc0 = max3abs(acc0, d.x, d.y);
            d = pk_add(a23, nb0[2 * q + 1]); acc0 = max3abs(acc0, d.x, d.y);
            d = pk_add(a01, nb1[2 * q + 0]); acc1 = max3abs(acc1, d.x, d.y);
            d = pk_add(a23, nb1[2 * q + 1]); acc1 = max3abs(acc1, d.x, d.y);
        }
        // coalesced: wave writes 512B contiguous
        *reinterpret_cast<float2*>(C + (size_t)(r0 + r) * M + c) = make_float2(acc0, acc1);
    }
}

extern "C" void kernel_launch(void* const* d_in, const int* in_sizes, int n_in,
                              void* d_out, int out_size, void* d_ws, size_t ws_size,
                              hipStream_t stream) {
    const float* A = (const float*)d_in[0];
    const float* B = (const float*)d_in[1];
    float* C = (float*)d_out;
    const int N = in_sizes[0] / FD;   // 4096
    const int M = in_sizes[1] / FD;   // 4096
    dim3 grid(M / (BLK * CPT), N / RPB);   // 8 x 128 = 1024 blocks
    cheb_kernel<<<grid, BLK, 0, stream>>>(A, B, C, M);
}

// Round 4
// 43.556 us; speedup vs baseline: 1.1944x; 1.1944x over previous
//
#include <hip/hip_runtime.h>

#define FD 32          // feature dim
#define RPB 16         // rows per block
#define CPT 4          // cols per thread -> block covers 1024 cols
#define BLK 256        // threads per block

// packed dual-fp32 add (B pre-negated in registers => computes a-b for 2 d's)
__device__ __forceinline__ float2 pk_add(float2 a, float2 b) {
    float2 r;
    asm("v_pk_add_f32 %0, %1, %2" : "=v"(r) : "v"(a), "v"(b));
    return r;
}
// acc = max(acc, |x|, |y|) in ONE VALU inst (abs = free VOP3 input modifier)
__device__ __forceinline__ float max3abs(float a, float x, float y) {
    float r;
    asm("v_max3_f32 %0, %1, abs(%2), abs(%3)" : "=v"(r) : "v"(a), "v"(x), "v"(y));
    return r;
}

__global__ __launch_bounds__(256) void cheb_kernel(
    const float* __restrict__ A, const float* __restrict__ B,
    float* __restrict__ C, int M)
{
    const int tid = threadIdx.x;
    const int c0  = blockIdx.x * (BLK * CPT) + tid * CPT;  // 4 output cols
    const int r0  = blockIdx.y * RPB;

    // ---- This thread's 4 B columns, negated, held in 64 VGPRs for the whole block.
    float2 nb[CPT][FD / 2];
#pragma unroll
    for (int j = 0; j < CPT; ++j) {
        const float* brow = B + (size_t)(c0 + j) * FD;
#pragma unroll
        for (int q = 0; q < 8; ++q) {
            const float4 v = *reinterpret_cast<const float4*>(brow + q * 4);
            nb[j][2 * q + 0] = make_float2(-v.x, -v.y);
            nb[j][2 * q + 1] = make_float2(-v.z, -v.w);
        }
    }

    // ---- Stream A rows; each 16B A-load feeds 4 output columns (TA-issue amortized).
#pragma unroll 2
    for (int r = 0; r < RPB; ++r) {
        const float* arow = A + (size_t)(r0 + r) * FD;
        float acc0 = 0.0f, acc1 = 0.0f, acc2 = 0.0f, acc3 = 0.0f;
#pragma unroll
        for (int q = 0; q < 8; ++q) {
            const float4 av = *reinterpret_cast<const float4*>(arow + q * 4);
            const float2 a01 = make_float2(av.x, av.y);
            const float2 a23 = make_float2(av.z, av.w);
            float2 d;
            d = pk_add(a01, nb[0][2 * q + 0]); acc0 = max3abs(acc0, d.x, d.y);
            d = pk_add(a01, nb[1][2 * q + 0]); acc1 = max3abs(acc1, d.x, d.y);
            d = pk_add(a01, nb[2][2 * q + 0]); acc2 = max3abs(acc2, d.x, d.y);
            d = pk_add(a01, nb[3][2 * q + 0]); acc3 = max3abs(acc3, d.x, d.y);
            d = pk_add(a23, nb[0][2 * q + 1]); acc0 = max3abs(acc0, d.x, d.y);
            d = pk_add(a23, nb[1][2 * q + 1]); acc1 = max3abs(acc1, d.x, d.y);
            d = pk_add(a23, nb[2][2 * q + 1]); acc2 = max3abs(acc2, d.x, d.y);
            d = pk_add(a23, nb[3][2 * q + 1]); acc3 = max3abs(acc3, d.x, d.y);
        }
        // coalesced: wave writes 1KB contiguous
        float4 o; o.x = acc0; o.y = acc1; o.z = acc2; o.w = acc3;
        *reinterpret_cast<float4*>(C + (size_t)(r0 + r) * M + c0) = o;
    }
}

extern "C" void kernel_launch(void* const* d_in, const int* in_sizes, int n_in,
                              void* d_out, int out_size, void* d_ws, size_t ws_size,
                              hipStream_t stream) {
    const float* A = (const float*)d_in[0];
    const float* B = (const float*)d_in[1];
    float* C = (float*)d_out;
    const int N = in_sizes[0] / FD;   // 4096
    const int M = in_sizes[1] / FD;   // 4096
    dim3 grid(M / (BLK * CPT), N / RPB);   // 4 x 256 = 1024 blocks
    cheb_kernel<<<grid, BLK, 0, stream>>>(A, B, C, M);
}